// Round 9
// baseline (187.189 us; speedup 1.0000x reference)
//
#include <hip/hip_runtime.h>

#define Bn 8
#define Vn 3
#define Hn 512
#define Wn 640
#define Nn (Hn * Wn)
#define PX 8                      // pixels per thread in predicate phase
#define TPB 256
#define XBLKS (Nn / (TPB * PX))   // 160 blocks per (b,i)
#define GRIDN (XBLKS * Vn * Bn)   // 3840 blocks

struct __attribute__((aligned(4))) fpair { float a, b; };

// ---------- 4x4 helpers (row-major float[16]) ----------
__device__ __forceinline__ void mat4_inv(const float* m, float* o) {
    float inv[16];
    inv[0]  =  m[5]*m[10]*m[15] - m[5]*m[11]*m[14] - m[9]*m[6]*m[15] + m[9]*m[7]*m[14] + m[13]*m[6]*m[11] - m[13]*m[7]*m[10];
    inv[4]  = -m[4]*m[10]*m[15] + m[4]*m[11]*m[14] + m[8]*m[6]*m[15] - m[8]*m[7]*m[14] - m[12]*m[6]*m[11] + m[12]*m[7]*m[10];
    inv[8]  =  m[4]*m[9]*m[15]  - m[4]*m[11]*m[13] - m[8]*m[5]*m[15] + m[8]*m[7]*m[13] + m[12]*m[5]*m[11] - m[12]*m[7]*m[9];
    inv[12] = -m[4]*m[9]*m[14]  + m[4]*m[10]*m[13] + m[8]*m[5]*m[14] - m[8]*m[6]*m[13] - m[12]*m[5]*m[10] + m[12]*m[6]*m[9];
    inv[1]  = -m[1]*m[10]*m[15] + m[1]*m[11]*m[14] + m[9]*m[2]*m[15] - m[9]*m[3]*m[14] - m[13]*m[2]*m[11] + m[13]*m[3]*m[10];
    inv[5]  =  m[0]*m[10]*m[15] - m[0]*m[11]*m[14] - m[8]*m[2]*m[15] + m[8]*m[3]*m[14] + m[12]*m[2]*m[11] - m[12]*m[3]*m[10];
    inv[9]  = -m[0]*m[9]*m[15]  + m[0]*m[11]*m[13] + m[8]*m[1]*m[15] - m[8]*m[3]*m[13] - m[12]*m[1]*m[11] + m[12]*m[3]*m[9];
    inv[13] =  m[0]*m[9]*m[14]  - m[0]*m[10]*m[13] - m[8]*m[1]*m[14] + m[8]*m[2]*m[13] + m[12]*m[1]*m[10] - m[12]*m[2]*m[9];
    inv[2]  =  m[1]*m[6]*m[15]  - m[1]*m[7]*m[14]  - m[5]*m[2]*m[15] + m[5]*m[3]*m[14] + m[13]*m[2]*m[7]  - m[13]*m[3]*m[6];
    inv[6]  = -m[0]*m[6]*m[15]  + m[0]*m[7]*m[14]  + m[4]*m[2]*m[15] - m[4]*m[3]*m[14] - m[12]*m[2]*m[7]  + m[12]*m[3]*m[6];
    inv[10] =  m[0]*m[5]*m[15]  - m[0]*m[7]*m[13]  - m[4]*m[1]*m[15] + m[4]*m[3]*m[13] + m[12]*m[1]*m[7]  - m[12]*m[3]*m[5];
    inv[14] = -m[0]*m[5]*m[14]  + m[0]*m[6]*m[13]  + m[4]*m[1]*m[14] - m[4]*m[2]*m[13] - m[12]*m[1]*m[6]  + m[12]*m[2]*m[5];
    inv[3]  = -m[1]*m[6]*m[11]  + m[1]*m[7]*m[10]  + m[5]*m[2]*m[11] - m[5]*m[3]*m[10] - m[9]*m[2]*m[7]   + m[9]*m[3]*m[6];
    inv[7]  =  m[0]*m[6]*m[11]  - m[0]*m[7]*m[10]  - m[4]*m[2]*m[11] + m[4]*m[3]*m[10] + m[8]*m[2]*m[7]   - m[8]*m[3]*m[6];
    inv[11] = -m[0]*m[5]*m[11]  + m[0]*m[7]*m[9]   + m[4]*m[1]*m[11] - m[4]*m[3]*m[9]  - m[8]*m[1]*m[7]   + m[8]*m[3]*m[5];
    inv[15] =  m[0]*m[5]*m[10]  - m[0]*m[6]*m[9]   - m[4]*m[1]*m[10] + m[4]*m[2]*m[9]  + m[8]*m[1]*m[6]   - m[8]*m[2]*m[5];
    float det = m[0]*inv[0] + m[1]*inv[4] + m[2]*inv[8] + m[3]*inv[12];
    float rdet = 1.0f / det;
    for (int k = 0; k < 16; ++k) o[k] = inv[k] * rdet;
}

__device__ __forceinline__ void mat4_mul(const float* a, const float* b, float* c) {
    for (int r = 0; r < 4; ++r)
        for (int col = 0; col < 4; ++col) {
            float s = 0.0f;
            for (int k = 0; k < 4; ++k) s = fmaf(a[r*4 + k], b[k*4 + col], s);
            c[r*4 + col] = s;
        }
}

// ---------- Stage 0: P matrices; zeroes accum + ticket counter ----------
__global__ void compute_P_kernel(const float* __restrict__ K,
                                 const float* __restrict__ RT,
                                 float* __restrict__ P,
                                 float* __restrict__ ws_head) {
    int idx = blockIdx.x * blockDim.x + threadIdx.x;
    if (idx < 32) ws_head[idx] = 0.0f;                 // accum[24] + counter + pad
    if (idx >= Bn * Vn * Vn) return;
    int b  = idx / (Vn * Vn);
    int ij = idx % (Vn * Vn);
    int i  = ij / Vn;
    int j  = ij % Vn;

    float Kb[16], Kinv[16], RTj[16], RTi[16], RTiinv[16], t1[16], t2[16], Pm[16];
    for (int k = 0; k < 16; ++k) Kb[k]  = K[b * 16 + k];
    for (int k = 0; k < 16; ++k) RTj[k] = RT[(b * Vn + j) * 16 + k];
    for (int k = 0; k < 16; ++k) RTi[k] = RT[(b * Vn + i) * 16 + k];
    mat4_inv(Kb, Kinv);
    mat4_inv(RTi, RTiinv);
    mat4_mul(Kb, RTj, t1);
    mat4_mul(t1, RTiinv, t2);
    mat4_mul(t2, Kinv, Pm);
    for (int k = 0; k < 16; ++k) P[idx * 16 + k] = Pm[k];
}

// ---------- Main: predicate -> LDS compaction -> dense gather; fused finalize ------
// pw == 1 analytically (all chain factors have exact [0,0,0,1] bottom rows) -> the
// reference's divide-by-proj[3] is a near-no-op; skip row 3 entirely.
// Predicate and consume phase use IDENTICAL fmaf expressions, so the active-set
// superset property is exact (no lost contributions).
__global__ __launch_bounds__(TPB) void loss_main_kernel(const float* __restrict__ pred,
                                                        const float* __restrict__ P,
                                                        float* __restrict__ accum,
                                                        unsigned* __restrict__ counter,
                                                        float* __restrict__ out) {
    // b = blockIdx.x % 8: XCD-batch L2 locality (one batch's 3 planes = 3.93 MB).
    const int id   = blockIdx.x;
    const int b    = id & 7;
    const int r    = id >> 3;
    const int i    = r % Vn;
    const int xblk = r / Vn;
    const int L    = b * Vn + i;

    __shared__ unsigned s_pk[TPB * PX];   // packed x | y<<16  (8 KB)
    __shared__ float    s_pd[TPB * PX];   // depth             (8 KB)
    __shared__ unsigned s_cnt;
    if (threadIdx.x == 0) s_cnt = 0u;
    __syncthreads();

    const int base = (xblk * TPB + threadIdx.x) * PX;
    const int yrow = base / Wn;           // PX=8 divides 640: no row wrap per thread
    const int xcol = base - yrow * Wn;
    const float fy = (float)yrow;

    const float* dptr = pred + (size_t)L * Nn + base;
    float dv[PX];
    {
        const float4 a0 = *reinterpret_cast<const float4*>(dptr);
        const float4 a1 = *reinterpret_cast<const float4*>(dptr + 4);
        dv[0] = a0.x; dv[1] = a0.y; dv[2] = a0.z; dv[3] = a0.w;
        dv[4] = a1.x; dv[5] = a1.y; dv[6] = a1.z; dv[7] = a1.w;
    }

    // block-uniform P rows 0..2 for the 3 pairs
    float Q[Vn][12];
    #pragma unroll
    for (int j = 0; j < Vn; ++j) {
        const float* Pm = P + (size_t)(L * Vn + j) * 16;
        #pragma unroll
        for (int k = 0; k < 12; ++k) Q[j][k] = Pm[k];
    }

    // ---- phase 1: predicate + ballot compaction into LDS ----
    const int lane = threadIdx.x & 63;
    {
        // hoist per-row (fy) constants for the predicate
        float RX[Vn], RY[Vn];
        #pragma unroll
        for (int j = 0; j < Vn; ++j) {
            RX[j] = fmaf(Q[j][1], fy, Q[j][2]);
            RY[j] = fmaf(Q[j][5], fy, Q[j][6]);
        }
        #pragma unroll
        for (int k = 0; k < PX; ++k) {
            const float d  = dv[k];
            const float fx = (float)(xcol + k);
            bool act = false;
            #pragma unroll
            for (int j = 0; j < Vn; ++j) {
                const float X = fmaf(d, fmaf(Q[j][0], fx, RX[j]), Q[j][3]);
                const float Y = fmaf(d, fmaf(Q[j][4], fx, RY[j]), Q[j][7]);
                act |= (X >= 0.0f) & (X <= (float)(Wn - 1)) &
                       (Y >= 0.0f) & (Y <= (float)(Hn - 1));
            }
            const unsigned long long m = __ballot(act);
            const int cnt = __popcll(m);
            unsigned wbase = 0;
            if (lane == 0 && cnt) wbase = atomicAdd(&s_cnt, (unsigned)cnt);
            wbase = (unsigned)__shfl((int)wbase, 0, 64);
            if (act) {
                const int pr = __popcll(m & ((1ULL << lane) - 1ULL));
                s_pk[wbase + pr] = (unsigned)(xcol + k) | ((unsigned)yrow << 16);
                s_pd[wbase + pr] = d;
            }
        }
    }
    __syncthreads();
    const unsigned n = s_cnt;

    // ---- phase 2: dense branchless processing of active records ----
    const float cW = (float)Wn / (float)(Wn - 1);
    const float cH = (float)Hn / (float)(Hn - 1);
    float num[Vn] = {0.0f, 0.0f, 0.0f};
    float den[Vn] = {0.0f, 0.0f, 0.0f};

    for (unsigned t = threadIdx.x; t < n; t += TPB) {
        const unsigned pk = s_pk[t];
        const float d   = s_pd[t];
        const float fx  = (float)(pk & 0xffffu);
        const float fyr = (float)(pk >> 16);

        #pragma unroll
        for (int j = 0; j < Vn; ++j) {
            // identical fmaf structure to the predicate
            const float RXd = fmaf(Q[j][1], fyr, Q[j][2]);
            const float RYd = fmaf(Q[j][5], fyr, Q[j][6]);
            const float RZd = fmaf(Q[j][9], fyr, Q[j][10]);
            const float X = fmaf(d, fmaf(Q[j][0], fx, RXd), Q[j][3]);
            const float Y = fmaf(d, fmaf(Q[j][4], fx, RYd), Q[j][7]);
            const float Z = fmaf(d, fmaf(Q[j][8], fx, RZd), Q[j][11]);

            const bool inb = (X >= 0.0f) & (X <= (float)(Wn - 1)) &
                             (Y >= 0.0f) & (Y <= (float)(Hn - 1));

            const float ix = fmaf(X, cW, -0.5f);
            const float iy = fmaf(Y, cH, -0.5f);
            const float x0f = floorf(ix);
            const float y0f = floorf(iy);
            const float wx1 = ix - x0f;
            const float wy1 = iy - y0f;
            const float wx0 = 1.0f - wx1;
            const float wy0 = 1.0f - wy1;
            const int x0 = (int)x0f;
            const int y0 = (int)y0f;
            const int x1 = x0 + 1;
            const int y1 = y0 + 1;
            const int cx  = min(max(x0, 0), Wn - 2);
            const int cy0 = min(max(y0, 0), Hn - 1);
            const int cy1 = min(max(y1, 0), Hn - 1);
            const bool xlo = (x0 >= 0);
            const bool xhi = (x0 <= Wn - 2);

            const float* img = pred + (size_t)(b * Vn + j) * Nn;
            const fpair q0 = *reinterpret_cast<const fpair*>(img + (cy0 * Wn + cx));
            const fpair q1 = *reinterpret_cast<const fpair*>(img + (cy1 * Wn + cx));
            const float c00 = xhi ? q0.a : q0.b;
            const float c10 = xlo ? q0.b : q0.a;
            const float c01 = xhi ? q1.a : q1.b;
            const float c11 = xlo ? q1.b : q1.a;

            const float wx0v = (inb && xlo)       ? wx0 : 0.0f;
            const float wx1v = (inb && (x1 < Wn)) ? wx1 : 0.0f;
            const float wy0v = (inb && (y0 >= 0)) ? wy0 : 0.0f;
            const float wy1v = (inb && (y1 < Hn)) ? wy1 : 0.0f;

            const float warped = wy0v * fmaf(wx0v, c00, wx1v * c10)
                               + wy1v * fmaf(wx0v, c01, wx1v * c11);
            const float Zs = inb ? Z : 0.0f;
            num[j] += fabsf(warped - Zs);
            den[j] += inb ? 1.0f : 0.0f;
        }
    }

    // ---- reduction: wave-64 shuffle over 6 accumulators ----
    #pragma unroll
    for (int off = 32; off > 0; off >>= 1) {
        #pragma unroll
        for (int j = 0; j < Vn; ++j) {
            num[j] += __shfl_down(num[j], off, 64);
            den[j] += __shfl_down(den[j], off, 64);
        }
    }
    __shared__ float s_red[4][2 * Vn];
    __shared__ int s_last;
    const int wid = threadIdx.x >> 6;
    if (lane == 0) {
        #pragma unroll
        for (int j = 0; j < Vn; ++j) {
            s_red[wid][2 * j + 0] = num[j];
            s_red[wid][2 * j + 1] = den[j];
        }
    }
    __syncthreads();
    if (threadIdx.x < 2 * Vn) {
        const int slot = threadIdx.x;
        const float v = s_red[0][slot] + s_red[1][slot] + s_red[2][slot] + s_red[3][slot];
        const int j = slot >> 1;
        const int comp = slot & 1;
        atomicAdd(&accum[(i * Vn + j) * 2 + comp], v);
    }
    __syncthreads();
    if (threadIdx.x == 0) {
        __threadfence();
        const unsigned old = atomicAdd(counter, 1u);
        s_last = (old == (unsigned)(GRIDN - 1)) ? 1 : 0;
    }
    __syncthreads();
    if (s_last && threadIdx.x == 0) {
        float tt = 0.0f;
        for (int pr = 0; pr < Vn * Vn; ++pr) {
            const float nn = atomicAdd(&accum[pr * 2 + 0], 0.0f);
            const float dd = atomicAdd(&accum[pr * 2 + 1], 0.0f);
            tt += nn / fmaxf(dd, 1.0f);
        }
        out[0] = tt;
    }
}

extern "C" void kernel_launch(void* const* d_in, const int* in_sizes, int n_in,
                              void* d_out, int out_size, void* d_ws, size_t ws_size,
                              hipStream_t stream) {
    const float* pred = (const float*)d_in[0];   // (B,V,H,W)
    const float* K    = (const float*)d_in[1];   // (B,4,4)
    const float* RT   = (const float*)d_in[2];   // (B,V,4,4)
    float* out = (float*)d_out;

    float*    accum   = (float*)d_ws;            // 24 floats (num,den per pair)
    unsigned* counter = (unsigned*)d_ws + 24;    // ticket counter
    float*    P       = (float*)d_ws + 32;       // 1152 floats

    compute_P_kernel<<<1, 128, 0, stream>>>(K, RT, P, (float*)d_ws);
    loss_main_kernel<<<GRIDN, TPB, 0, stream>>>(pred, P, accum, counter, out);
}